// Round 1
// baseline (142.075 us; speedup 1.0000x reference)
//
#include <hip/hip_runtime.h>
#include <math.h>

// Problem: SHLightRotateDecorator — B samples, each projects a rotating
// gaussian light lobe over a 16x32 sphere grid onto 25 SH basis functions,
// output repeated x3 (RGB) -> [B, 75] f32.
//
// Key restructure: lm = log(1e-5 + exp(-4*acos(dot)^2)) <= ~0, so
// logsumexp needs no max-shift: lse = log(sum e_p) with e_p = 1e-5+exp(-4a^2).
// The normalization is linear post-log:
//   proj_k = sum_p lm_p * w[k,p]  +  ((7 - lse) + 0.001) * wsum_k
// -> single pass over pixels, no cross-lane logsumexp.

#define PI_A 3.1415926
#define NPI  3.14159265358979323846

// ws layout (floats):
//   [0, 16384)      wT[512][32]   (w transposed, k-padded to 32; k>=25 are 0)
//   [16384, 17408)  dr[512][2]    (dr0 = sin(th)sin(ph), dr2 = sin(th)cos(ph))
//   [17408, 17440)  wsum[32]
#define WT_OFF   0
#define DR_OFF   16384
#define WSUM_OFF 17408
#define WS_FLOATS 17440

__global__ __launch_bounds__(256) void sh_prep_kernel(
        const float* __restrict__ bases, float* __restrict__ ws) {
    const int tid = threadIdx.x;  // single block of 256
    const float KC = (float)(NPI * NPI / 512.0);  // np.pi^2 / numel (true pi!)

    // wT[p][k] = bases[k][p] * sin(th_row(p)) * KC   (f32 math, matching jnp)
    for (int idx = tid; idx < 512 * 32; idx += 256) {
        const int p = idx >> 5, k = idx & 31;
        float v = 0.0f;
        if (k < 25) {
            const int y = p >> 5;
            const float th = (float)(((double)y + 0.5) * PI_A / 16.0);
            v = bases[k * 512 + p] * sinf(th) * KC;
        }
        ws[WT_OFF + idx] = v;
    }
    // per-pixel ray dir components that matter (ldir.y == 0)
    for (int p = tid; p < 512; p += 256) {
        const int y = p >> 5, x = p & 31;
        const float th = (float)(((double)y + 0.5) * PI_A / 16.0);
        const float ph = (float)(((double)x + 0.5) * PI_A / 16.0);
        const float st = sinf(th);
        ws[DR_OFF + 2 * p]     = st * sinf(ph);  // dr0
        ws[DR_OFF + 2 * p + 1] = st * cosf(ph);  // dr2
    }
    // wsum[k] = sum_p w[k][p]  (recomputed from bases; independent of wT writes)
    if (tid < 32) {
        float s = 0.0f;
        if (tid < 25) {
            for (int p = 0; p < 512; ++p) {
                const int y = p >> 5;
                const float th = (float)(((double)y + 0.5) * PI_A / 16.0);
                s += bases[tid * 512 + p] * sinf(th) * KC;
            }
        }
        ws[WSUM_OFF + tid] = s;
    }
}

// One lane per sample; 4 waves/block split the 512 pixels (128 each).
// Pixel index is wave-uniform -> w/dr loads should be scalar (s_load) and
// feed v_fmac v,s,v. Partials combined through LDS at the end.
__global__ __launch_bounds__(256, 4) void sh_proj_kernel(
        const int* __restrict__ iternum_p, const float* __restrict__ ws,
        float* __restrict__ out, int B) {
    __shared__ float red[4][64][29];  // 29: odd stride -> conflict-free-ish

    const int tid  = threadIdx.x;
    const int lane = tid & 63;
    const int wv   = tid >> 6;
    const int b    = blockIdx.x * 64 + lane;  // sample owned by this lane

    // Rotating light dir: ph0 must be evaluated in f64 (it's ~2e6 radians;
    // f32 ulp there is 0.125 rad). Matches numpy's f64 sin/cos then f32 cast.
    const long long n = (long long)(*iternum_p) * (long long)B
                      + (long long)(b < B ? b : 0);
    const double ph0 = ((double)n * 2.0) * PI_A / 200.0;
    const float sld = (float)sin(ph0);
    const float cld = (float)cos(ph0);

    // wave-uniform pixel base (readfirstlane -> SGPR so the compiler can
    // prove uniformity of all table addresses)
    const int pbase = __builtin_amdgcn_readfirstlane(wv * 128);

    float part[28];
#pragma unroll
    for (int k = 0; k < 28; ++k) part[k] = 0.0f;
    float S = 0.0f;

    for (int i = 0; i < 128; ++i) {
        const int p = pbase + i;
        const float drx = ws[DR_OFF + 2 * p];
        const float drz = ws[DR_OFF + 2 * p + 1];
        float dot = sld * drx + cld * drz;        // ldir.y == 0
        dot = fminf(1.0f, fmaxf(-1.0f, dot));
        const float a  = acosf(dot);
        const float e  = 1e-5f + __expf(-4.0f * a * a);
        const float lm = __logf(e);
        S += e;
        const float* wr = ws + WT_OFF + (p << 5);
#pragma unroll
        for (int q = 0; q < 7; ++q) {
            part[q * 4 + 0] = fmaf(lm, wr[q * 4 + 0], part[q * 4 + 0]);
            part[q * 4 + 1] = fmaf(lm, wr[q * 4 + 1], part[q * 4 + 1]);
            part[q * 4 + 2] = fmaf(lm, wr[q * 4 + 2], part[q * 4 + 2]);
            part[q * 4 + 3] = fmaf(lm, wr[q * 4 + 3], part[q * 4 + 3]);
        }
    }

#pragma unroll
    for (int k = 0; k < 25; ++k) red[wv][lane][k] = part[k];
    red[wv][lane][25] = S;
    __syncthreads();

    if (wv == 0 && b < B) {
        const float St = red[0][lane][25] + red[1][lane][25]
                       + red[2][lane][25] + red[3][lane][25];
        const float C = (7.0f - logf(St)) + 0.001f;  // (lm+7-lse)+0.001 constant part
        float* ob = out + (size_t)b * 75;
#pragma unroll
        for (int k = 0; k < 25; ++k) {
            const float v = red[0][lane][k] + red[1][lane][k]
                          + red[2][lane][k] + red[3][lane][k]
                          + C * ws[WSUM_OFF + k];
            ob[3 * k]     = v;   // jnp.repeat(..., 3): RGB copies
            ob[3 * k + 1] = v;
            ob[3 * k + 2] = v;
        }
    }
}

extern "C" void kernel_launch(void* const* d_in, const int* in_sizes, int n_in,
                              void* d_out, int out_size, void* d_ws, size_t ws_size,
                              hipStream_t stream) {
    // inputs: [0] lightid (int32, B — values unused), [1] iternum (int32 scalar),
    //         [2] bases (f32, 25*16*32)
    const int*   iternum = (const int*)d_in[1];
    const float* bases   = (const float*)d_in[2];
    float* out = (float*)d_out;
    float* ws  = (float*)d_ws;
    const int B = in_sizes[0];

    hipLaunchKernelGGL(sh_prep_kernel, dim3(1), dim3(256), 0, stream, bases, ws);
    hipLaunchKernelGGL(sh_proj_kernel, dim3((B + 63) / 64), dim3(256), 0, stream,
                       iternum, ws, out, B);
}

// Round 2
// 69.154 us; speedup vs baseline: 2.0545x; 2.0545x over previous
//
#include <hip/hip_runtime.h>
#include <math.h>

// Problem: SHLightRotateDecorator — B samples, each projects a rotating
// gaussian light lobe over a 16x32 sphere grid onto 25 SH basis functions,
// output repeated x3 (RGB) -> [B, 75] f32.
//
// Key restructure: lm = log(1e-5 + exp(-4*acos(dot)^2)) <= ~0, so
// logsumexp needs no max-shift: lse = log(sum e_p) with e_p = 1e-5+exp(-4a^2).
// The normalization is linear post-log:
//   proj_k = sum_p lm_p * w[k,p]  +  ((7 - lse) + 0.001) * wsum_k
// -> single pass over pixels, no cross-lane logsumexp.

#define PI_A 3.1415926
#define NPI  3.14159265358979323846

// ws layout (floats):
//   [0, 16384)      wT[512][32]   (w transposed, k-padded to 32; k>=25 are 0)
//   [16384, 17408)  dr[512][2]    (dr0 = sin(th)sin(ph), dr2 = sin(th)cos(ph))
//   [17408, 17440)  wsum[32]
#define WT_OFF   0
#define DR_OFF   16384
#define WSUM_OFF 17408
#define WS_FLOATS 17440

// Parallel prep: R1 fix — the old single-block prep was 90 us (serial wsum
// loop, occupancy 0.016%). Now 91 blocks: [0,64) one thread per wT element,
// [64,66) dr, [66,91) one block per k reducing wsum via shuffle+LDS tree.
__global__ __launch_bounds__(256) void sh_prep_kernel(
        const float* __restrict__ bases, float* __restrict__ ws) {
    const int tid = threadIdx.x;
    const int blk = blockIdx.x;
    const float KC = (float)(NPI * NPI / 512.0);  // np.pi^2 / numel (true pi!)

    if (blk < 64) {
        // wT[p][k] = bases[k][p] * sin(th_row(p)) * KC  (f32 math, matching jnp)
        const int idx = blk * 256 + tid;
        const int p = idx >> 5, k = idx & 31;
        float v = 0.0f;
        if (k < 25) {
            const int y = p >> 5;
            const float th = (float)(((double)y + 0.5) * PI_A / 16.0);
            v = bases[k * 512 + p] * sinf(th) * KC;
        }
        ws[WT_OFF + idx] = v;
    } else if (blk < 66) {
        // per-pixel ray dir components that matter (ldir.y == 0)
        const int p = (blk - 64) * 256 + tid;
        const int y = p >> 5, x = p & 31;
        const float th = (float)(((double)y + 0.5) * PI_A / 16.0);
        const float ph = (float)(((double)x + 0.5) * PI_A / 16.0);
        const float st = sinf(th);
        ws[DR_OFF + 2 * p]     = st * sinf(ph);  // dr0
        ws[DR_OFF + 2 * p + 1] = st * cosf(ph);  // dr2
    } else {
        // wsum[k] = sum_p w[k][p], one block per k, tree reduction
        const int k = blk - 66;
        float s = 0.0f;
        for (int p = tid; p < 512; p += 256) {
            const int y = p >> 5;
            const float th = (float)(((double)y + 0.5) * PI_A / 16.0);
            s += bases[k * 512 + p] * sinf(th) * KC;
        }
#pragma unroll
        for (int off = 32; off; off >>= 1) s += __shfl_down(s, off, 64);
        __shared__ float red[4];
        if ((tid & 63) == 0) red[tid >> 6] = s;
        __syncthreads();
        if (tid == 0) ws[WSUM_OFF + k] = red[0] + red[1] + red[2] + red[3];
    }
}

// One lane per sample; 4 waves/block split the 512 pixels (128 each).
// Pixel index is wave-uniform -> w/dr loads are scalar (s_load) and
// feed v_fmac v,s,v. Partials combined through LDS at the end.
__global__ __launch_bounds__(256, 4) void sh_proj_kernel(
        const int* __restrict__ iternum_p, const float* __restrict__ ws,
        float* __restrict__ out, int B) {
    __shared__ float red[4][64][29];  // 29: odd stride -> conflict-free-ish

    const int tid  = threadIdx.x;
    const int lane = tid & 63;
    const int wv   = tid >> 6;
    const int b    = blockIdx.x * 64 + lane;  // sample owned by this lane

    // Rotating light dir: ph0 must be evaluated in f64 (it's ~2e6 radians;
    // f32 ulp there is 0.125 rad). Matches numpy's f64 sin/cos then f32 cast.
    const long long n = (long long)(*iternum_p) * (long long)B
                      + (long long)(b < B ? b : 0);
    const double ph0 = ((double)n * 2.0) * PI_A / 200.0;
    const float sld = (float)sin(ph0);
    const float cld = (float)cos(ph0);

    // wave-uniform pixel base (readfirstlane -> SGPR so the compiler can
    // prove uniformity of all table addresses)
    const int pbase = __builtin_amdgcn_readfirstlane(wv * 128);

    float part[28];
#pragma unroll
    for (int k = 0; k < 28; ++k) part[k] = 0.0f;
    float S = 0.0f;

    for (int i = 0; i < 128; ++i) {
        const int p = pbase + i;
        const float drx = ws[DR_OFF + 2 * p];
        const float drz = ws[DR_OFF + 2 * p + 1];
        float dot = sld * drx + cld * drz;        // ldir.y == 0
        dot = fminf(1.0f, fmaxf(-1.0f, dot));
        const float a  = acosf(dot);
        const float e  = 1e-5f + __expf(-4.0f * a * a);
        const float lm = __logf(e);
        S += e;
        const float* wr = ws + WT_OFF + (p << 5);
#pragma unroll
        for (int q = 0; q < 7; ++q) {
            part[q * 4 + 0] = fmaf(lm, wr[q * 4 + 0], part[q * 4 + 0]);
            part[q * 4 + 1] = fmaf(lm, wr[q * 4 + 1], part[q * 4 + 1]);
            part[q * 4 + 2] = fmaf(lm, wr[q * 4 + 2], part[q * 4 + 2]);
            part[q * 4 + 3] = fmaf(lm, wr[q * 4 + 3], part[q * 4 + 3]);
        }
    }

#pragma unroll
    for (int k = 0; k < 25; ++k) red[wv][lane][k] = part[k];
    red[wv][lane][25] = S;
    __syncthreads();

    if (wv == 0 && b < B) {
        const float St = red[0][lane][25] + red[1][lane][25]
                       + red[2][lane][25] + red[3][lane][25];
        const float C = (7.0f - logf(St)) + 0.001f;  // (lm+7-lse)+0.001 constant part
        float* ob = out + (size_t)b * 75;
#pragma unroll
        for (int k = 0; k < 25; ++k) {
            const float v = red[0][lane][k] + red[1][lane][k]
                          + red[2][lane][k] + red[3][lane][k]
                          + C * ws[WSUM_OFF + k];
            ob[3 * k]     = v;   // jnp.repeat(..., 3): RGB copies
            ob[3 * k + 1] = v;
            ob[3 * k + 2] = v;
        }
    }
}

extern "C" void kernel_launch(void* const* d_in, const int* in_sizes, int n_in,
                              void* d_out, int out_size, void* d_ws, size_t ws_size,
                              hipStream_t stream) {
    // inputs: [0] lightid (int32, B — values unused), [1] iternum (int32 scalar),
    //         [2] bases (f32, 25*16*32)
    const int*   iternum = (const int*)d_in[1];
    const float* bases   = (const float*)d_in[2];
    float* out = (float*)d_out;
    float* ws  = (float*)d_ws;
    const int B = in_sizes[0];

    hipLaunchKernelGGL(sh_prep_kernel, dim3(91), dim3(256), 0, stream, bases, ws);
    hipLaunchKernelGGL(sh_proj_kernel, dim3((B + 63) / 64), dim3(256), 0, stream,
                       iternum, ws, out, B);
}

// Round 3
// 36.114 us; speedup vs baseline: 3.9341x; 1.9149x over previous
//
#include <hip/hip_runtime.h>
#include <math.h>

// SHLightRotateDecorator — B samples x 512 sphere pixels -> 25 SH coeffs (x3 RGB).
//
// R2 restructure: proj[b][k] = sum_p lm[b][p]*w[k][p] is a [Bx512]x[512x25] GEMM
// -> fused MFMA (16x16x32 f16). Each wave owns 16 samples; per 32-pixel K-slice
// each lane computes its 8 lm values DIRECTLY in A-fragment layout (pixel choice
// == fragment slot choice, no shuffles), cvt fp16, 2 MFMAs (coeff halves 0..15 /
// 16..31; cols >=25 are zero-padded in w). w is pre-packed into B-fragment
// layout by prep (fp16, 32KB, L1-resident). A and B use the SAME (lane>>4,j)->k
// map, so correctness is invariant to the hardware k-permutation (k_A == k_B by
// ISA symmetry). C/D layout: col=lane&15, row=(lane>>4)*4+reg (HW-verified).
//
// lm math (single pass, no 2-pass logsumexp): lm = log(1e-5 + exp(-4*acos(dot)^2))
// is <= ~1e-5, so lse = log(S) with S = sum e_p directly, and the normalization
// is linear post-log: proj_k = sum_p lm_p*w[k,p] + ((7 - log S) + 0.001)*wsum_k.

#define PI_A 3.1415926
#define NPI  3.14159265358979323846

typedef _Float16 f16x8 __attribute__((ext_vector_type(8)));
typedef float    f32x4 __attribute__((ext_vector_type(4)));

#if __has_builtin(__builtin_amdgcn_sqrtf)
#define FSQRT __builtin_amdgcn_sqrtf
#else
#define FSQRT sqrtf
#endif
#if __has_builtin(__builtin_amdgcn_exp2f)
#define FEXP2 __builtin_amdgcn_exp2f
#else
#define FEXP2 exp2f
#endif
#if __has_builtin(__builtin_amdgcn_logf)
#define FLOG2 __builtin_amdgcn_logf
#else
#define FLOG2 log2f
#endif

// ws layout (floats):
//   [0, 8192)     wfrag fp16[16 slices][2 halves][64 lanes][8]  (B-frags, 32KB)
//   [8192, 9216)  dr float2[512]: (sin(th)sin(ph), sin(th)cos(ph))
//   [9216, 9248)  wsum f32[32]
#define WFRAG_OFF 0
#define DR_OFF    8192
#define WSUM_OFF  9216

__global__ __launch_bounds__(256) void sh_prep_kernel(
        const float* __restrict__ bases, float* __restrict__ ws) {
    const int tid = threadIdx.x;
    const int blk = blockIdx.x;
    const float KC = (float)(NPI * NPI / 512.0);  // np.pi^2 / numel (true pi!)

    if (blk < 8) {
        // B-fragment pack: t = (slice*2+half)*64 + lane; each thread 8 fp16.
        // B[k][n]: n = lane&15 -> coeff = half*16 + n; k-slot (lane>>4)*8+j
        // -> pixel = slice*32 + (lane>>4)*8 + j  (same map the A-side uses).
        const int t    = blk * 256 + tid;
        const int lane = t & 63;
        const int sh_  = t >> 6;
        const int slice = sh_ >> 1, half = sh_ & 1;
        const int coeff = half * 16 + (lane & 15);
        const int px0   = slice * 32 + ((lane >> 4) << 3);
        // pixel row y == slice (pixel = y*32 + x), so st is slice-uniform
        const float th  = (float)(((double)slice + 0.5) * PI_A / 16.0);
        const float stk = sinf(th) * KC;
        f16x8 v;
#pragma unroll
        for (int j = 0; j < 8; ++j) {
            float w = (coeff < 25) ? bases[coeff * 512 + px0 + j] * stk : 0.0f;
            v[j] = (_Float16)w;
        }
        ((f16x8*)(ws + WFRAG_OFF))[t] = v;
    } else if (blk < 10) {
        // per-pixel ray dir (ldir.y == 0 -> only x,z components matter)
        const int p = (blk - 8) * 256 + tid;
        const int y = p >> 5, x = p & 31;
        const float th = (float)(((double)y + 0.5) * PI_A / 16.0);
        const float ph = (float)(((double)x + 0.5) * PI_A / 16.0);
        const float st = sinf(th);
        ws[DR_OFF + 2 * p]     = st * sinf(ph);
        ws[DR_OFF + 2 * p + 1] = st * cosf(ph);
    } else {
        // wsum[k] (f32, exact), one block per k, shuffle+LDS tree
        const int k = blk - 10;
        float s = 0.0f;
        for (int p = tid; p < 512; p += 256) {
            const int y = p >> 5;
            const float th = (float)(((double)y + 0.5) * PI_A / 16.0);
            s += bases[k * 512 + p] * sinf(th) * KC;
        }
#pragma unroll
        for (int off = 32; off; off >>= 1) s += __shfl_down(s, off, 64);
        __shared__ float red[4];
        if ((tid & 63) == 0) red[tid >> 6] = s;
        __syncthreads();
        if (tid == 0) ws[WSUM_OFF + k] = red[0] + red[1] + red[2] + red[3];
    }
}

__global__ __launch_bounds__(256) void sh_proj_kernel(
        const int* __restrict__ iternum_p, const float* __restrict__ ws,
        float* __restrict__ out, int B) {
    const int tid  = threadIdx.x;
    const int lane = tid & 63;
    const int wv   = tid >> 6;
    const int m    = lane & 15;       // A row / C col
    const int rg   = lane >> 4;       // k-group selector
    const int gbase = blockIdx.x * 64 + wv * 16;  // 16 samples per wave
    const int b     = gbase + m;      // sample this lane evaluates lm for

    // ph0 in f64 (≈2e6 rad; f32 ulp there is 0.125 rad). Same op order as numpy.
    const long long n = (long long)(*iternum_p) * (long long)B
                      + (long long)(b < B ? b : 0);
    const double ph0 = ((double)n * 2.0) * PI_A / 200.0;
    const float sld = (float)sin(ph0);
    const float cld = (float)cos(ph0);

    const f16x8*  wfrag = (const f16x8*)(ws + WFRAG_OFF);
    const float4* drv   = (const float4*)(ws + DR_OFF);

    f32x4 acc0 = {0.f, 0.f, 0.f, 0.f};
    f32x4 acc1 = {0.f, 0.f, 0.f, 0.f};
    float S = 0.0f;
    const float c1  = -4.0f * 1.4426950408889634f;  // -4*log2(e) -> exp2
    const float ln2 = 0.6931471805599453f;

    for (int slice = 0; slice < 16; ++slice) {
        const f16x8 bf0 = wfrag[(slice * 2 + 0) * 64 + lane];
        const f16x8 bf1 = wfrag[(slice * 2 + 1) * 64 + lane];
        const int pbase = slice * 32 + (rg << 3);  // my 8 pixels this slice
        f16x8 af;
#pragma unroll
        for (int t = 0; t < 4; ++t) {
            const float4 d = drv[(pbase >> 1) + t];  // 2 pixels: (x,y),(z,w)
#pragma unroll
            for (int u = 0; u < 2; ++u) {
                const float drx = u ? d.z : d.x;
                const float drz = u ? d.w : d.y;
                float dot = fminf(1.0f, fmaxf(-1.0f, sld * drx + cld * drz));
                // fast acos (Hastings, |err|~1.8e-4 rad)
                const float ax = fabsf(dot);
                const float sq = FSQRT(1.0f - ax);
                const float P  = fmaf(fmaf(fmaf(-0.0187293f, ax, 0.0742610f),
                                           ax, -0.2121144f), ax, 1.5707288f);
                const float r  = sq * P;
                const float a  = (dot < 0.0f) ? (3.14159265f - r) : r;
                const float ex = FEXP2(a * a * c1);    // exp(-4 a^2)
                const float e  = 1e-5f + ex;
                S += e;
                const float lm = FLOG2(e) * ln2;
                af[2 * t + u] = (_Float16)lm;
            }
        }
        acc0 = __builtin_amdgcn_mfma_f32_16x16x32_f16(af, bf0, acc0, 0, 0, 0);
        acc1 = __builtin_amdgcn_mfma_f32_16x16x32_f16(af, bf1, acc1, 0, 0, 0);
    }

    // lanes {m, m+16, m+32, m+48} hold partial S of sample gbase+m
    S += __shfl_xor(S, 16, 64);
    S += __shfl_xor(S, 32, 64);
    const float C = (7.0f - FLOG2(S) * ln2) + 0.001f;

    const float wsum0 = ws[WSUM_OFF + m];
    const float wsum1 = ws[WSUM_OFF + 16 + m];
#pragma unroll
    for (int r = 0; r < 4; ++r) {
        const int row = (rg << 2) + r;           // C row = sample offset
        const float Cs = __shfl(C, row, 64);     // lane 'row' owns that sample's C
        const int s = gbase + row;
        if (s < B) {
            float* ob = out + (size_t)s * 75;
            const float v0 = acc0[r] + Cs * wsum0;
            ob[3 * m]     = v0;
            ob[3 * m + 1] = v0;
            ob[3 * m + 2] = v0;
            if (m <= 8) {
                const int k = 16 + m;
                const float v1 = acc1[r] + Cs * wsum1;
                ob[3 * k]     = v1;
                ob[3 * k + 1] = v1;
                ob[3 * k + 2] = v1;
            }
        }
    }
}

extern "C" void kernel_launch(void* const* d_in, const int* in_sizes, int n_in,
                              void* d_out, int out_size, void* d_ws, size_t ws_size,
                              hipStream_t stream) {
    // inputs: [0] lightid (int32, B — unused), [1] iternum (int32 scalar),
    //         [2] bases (f32, 25*16*32)
    const int*   iternum = (const int*)d_in[1];
    const float* bases   = (const float*)d_in[2];
    float* out = (float*)d_out;
    float* ws  = (float*)d_ws;
    const int B = in_sizes[0];

    hipLaunchKernelGGL(sh_prep_kernel, dim3(35), dim3(256), 0, stream, bases, ws);
    hipLaunchKernelGGL(sh_proj_kernel, dim3((B + 63) / 64), dim3(256), 0, stream,
                       iternum, ws, out, B);
}

// Round 4
// 24.685 us; speedup vs baseline: 5.7554x; 1.4630x over previous
//
#include <hip/hip_runtime.h>
#include <math.h>

// SHLightRotateDecorator — B samples x 512 sphere pixels -> 25 SH coeffs (x3 RGB).
//
// R2: proj[b][k] = sum_p lm[b][p]*w[k][p] as fused MFMA (16x16x32 f16); lane
// computes lm directly in A-fragment layout; w pre-packed into B-fragments.
// R3: ROW-SYMMETRY FOLD. th_y + th_{15-y} = PI_A and light.y == 0, so
// dot[y][x] == dot[15-y][x] exactly (up to sin(pi-PI_A) ~ 5e-8): the whole
// acos/exp/log chain is identical for row pairs. Fold the weights instead:
//   proj_k = sum_{y<8,x} lm[y][x] * (w[k][y][x] + w[k][15-y][x])
//   S      = 2 * sum_{y<8,x} e[y][x]
// -> K=256 (8 slices), half the transcendentals/VALU/MFMAs of R2.
//
// lm math (single pass): lm = log(1e-5 + exp(-4*acos(dot)^2)) <= ~1e-5 so
// lse = log(S) directly; normalization is linear post-log:
//   proj_k = sum lm*w~ + ((7 - log S) + 0.001)*wsum_k.

#define PI_A 3.1415926
#define NPI  3.14159265358979323846

typedef _Float16 f16x8 __attribute__((ext_vector_type(8)));
typedef float    f32x4 __attribute__((ext_vector_type(4)));

#if __has_builtin(__builtin_amdgcn_sqrtf)
#define FSQRT __builtin_amdgcn_sqrtf
#else
#define FSQRT sqrtf
#endif
#if __has_builtin(__builtin_amdgcn_exp2f)
#define FEXP2 __builtin_amdgcn_exp2f
#else
#define FEXP2 exp2f
#endif
#if __has_builtin(__builtin_amdgcn_logf)
#define FLOG2 __builtin_amdgcn_logf
#else
#define FLOG2 log2f
#endif

// ws layout (floats):
//   [0, 4096)     wfrag fp16[8 slices][2 halves][64 lanes][8]  (folded B-frags, 16KB)
//   [4096, 4608)  dr float2[256]: rows y<8 only: (sin(th)sin(ph), sin(th)cos(ph))
//   [4608, 4640)  wsum f32[32]  (sum over the FULL 512-pixel grid)
#define WFRAG_OFF 0
#define DR_OFF    4096
#define WSUM_OFF  4608

__global__ __launch_bounds__(256) void sh_prep_kernel(
        const float* __restrict__ bases, float* __restrict__ ws) {
    const int tid = threadIdx.x;
    const int blk = blockIdx.x;
    const float KC = (float)(NPI * NPI / 512.0);  // np.pi^2 / numel (true pi!)

    if (blk < 4) {
        // Folded B-fragment pack: t = (slice*2+half)*64 + lane, 8 fp16 each.
        // coeff = half*16 + (lane&15); k-slot (lane>>4)*8+j -> folded pixel
        // p~ = slice*32 + (lane>>4)*8 + j  (y = slice in [0,8), x = col).
        const int t    = blk * 256 + tid;
        const int lane = t & 63;
        const int sh_  = t >> 6;
        const int slice = sh_ >> 1, half = sh_ & 1;
        const int coeff = half * 16 + (lane & 15);
        const int col0  = (lane >> 4) << 3;
        const float th_lo = (float)(((double)slice + 0.5) * PI_A / 16.0);
        const float th_hi = (float)(((double)(15 - slice) + 0.5) * PI_A / 16.0);
        const float st_lo = sinf(th_lo) * KC;
        const float st_hi = sinf(th_hi) * KC;
        f16x8 v;
#pragma unroll
        for (int j = 0; j < 8; ++j) {
            float w = 0.0f;
            if (coeff < 25) {
                const int x = col0 + j;
                w = bases[coeff * 512 + slice * 32 + x] * st_lo
                  + bases[coeff * 512 + (15 - slice) * 32 + x] * st_hi;
            }
            v[j] = (_Float16)w;
        }
        ((f16x8*)(ws + WFRAG_OFF))[t] = v;
    } else if (blk == 4) {
        // per-pixel ray dir for rows y<8 (ldir.y == 0 -> only x,z matter)
        const int p = tid;              // [0,256)
        const int y = p >> 5, x = p & 31;
        const float th = (float)(((double)y + 0.5) * PI_A / 16.0);
        const float ph = (float)(((double)x + 0.5) * PI_A / 16.0);
        const float st = sinf(th);
        ws[DR_OFF + 2 * p]     = st * sinf(ph);
        ws[DR_OFF + 2 * p + 1] = st * cosf(ph);
    } else {
        // wsum[k] over the full 512 grid (f32), one block per k
        const int k = blk - 5;
        float s = 0.0f;
        for (int p = tid; p < 512; p += 256) {
            const int y = p >> 5;
            const float th = (float)(((double)y + 0.5) * PI_A / 16.0);
            s += bases[k * 512 + p] * sinf(th) * KC;
        }
#pragma unroll
        for (int off = 32; off; off >>= 1) s += __shfl_down(s, off, 64);
        __shared__ float red[4];
        if ((tid & 63) == 0) red[tid >> 6] = s;
        __syncthreads();
        if (tid == 0) ws[WSUM_OFF + k] = red[0] + red[1] + red[2] + red[3];
    }
}

__global__ __launch_bounds__(256) void sh_proj_kernel(
        const int* __restrict__ iternum_p, const float* __restrict__ ws,
        float* __restrict__ out, int B) {
    const int tid  = threadIdx.x;
    const int lane = tid & 63;
    const int wv   = tid >> 6;
    const int m    = lane & 15;       // A row / C col
    const int rg   = lane >> 4;       // k-group selector
    const int gbase = blockIdx.x * 64 + wv * 16;  // 16 samples per wave
    const int b     = gbase + m;      // sample this lane evaluates lm for

    // ph0 in f64 (~2e6 rad; f32 ulp there is 0.125 rad). Same op order as numpy.
    const long long n = (long long)(*iternum_p) * (long long)B
                      + (long long)(b < B ? b : 0);
    const double ph0 = ((double)n * 2.0) * PI_A / 200.0;
    const float sld = (float)sin(ph0);
    const float cld = (float)cos(ph0);

    const f16x8*  wfrag = (const f16x8*)(ws + WFRAG_OFF);
    const float4* drv   = (const float4*)(ws + DR_OFF);

    f32x4 acc0 = {0.f, 0.f, 0.f, 0.f};
    f32x4 acc1 = {0.f, 0.f, 0.f, 0.f};
    float S = 0.0f;
    const float c1  = -4.0f * 1.4426950408889634f;  // -4*log2(e) -> exp2
    const float ln2 = 0.6931471805599453f;

#pragma unroll
    for (int slice = 0; slice < 8; ++slice) {
        const f16x8 bf0 = wfrag[(slice * 2 + 0) * 64 + lane];
        const f16x8 bf1 = wfrag[(slice * 2 + 1) * 64 + lane];
        const int pbase = slice * 32 + (rg << 3);  // my 8 folded pixels
        f16x8 af;
#pragma unroll
        for (int t = 0; t < 4; ++t) {
            const float4 d = drv[(pbase >> 1) + t];  // 2 pixels: (x,y),(z,w)
#pragma unroll
            for (int u = 0; u < 2; ++u) {
                const float drx = u ? d.z : d.x;
                const float drz = u ? d.w : d.y;
                float dot = fminf(1.0f, fmaxf(-1.0f, sld * drx + cld * drz));
                // fast acos (Hastings, |err|~1.8e-4 rad)
                const float ax = fabsf(dot);
                const float sq = FSQRT(1.0f - ax);
                const float P  = fmaf(fmaf(fmaf(-0.0187293f, ax, 0.0742610f),
                                           ax, -0.2121144f), ax, 1.5707288f);
                const float r  = sq * P;
                const float a  = (dot < 0.0f) ? (3.14159265f - r) : r;
                const float ex = FEXP2(a * a * c1);    // exp(-4 a^2)
                const float e  = 1e-5f + ex;
                S += e;
                const float lm = FLOG2(e) * ln2;
                af[2 * t + u] = (_Float16)lm;
            }
        }
        acc0 = __builtin_amdgcn_mfma_f32_16x16x32_f16(af, bf0, acc0, 0, 0, 0);
        acc1 = __builtin_amdgcn_mfma_f32_16x16x32_f16(af, bf1, acc1, 0, 0, 0);
    }

    // lanes {m, m+16, m+32, m+48} hold partial S of sample gbase+m; full grid = 2x
    S += __shfl_xor(S, 16, 64);
    S += __shfl_xor(S, 32, 64);
    const float C = (7.0f - FLOG2(2.0f * S) * ln2) + 0.001f;

    const float wsum0 = ws[WSUM_OFF + m];
    const float wsum1 = ws[WSUM_OFF + 16 + m];
#pragma unroll
    for (int r = 0; r < 4; ++r) {
        const int row = (rg << 2) + r;           // C row = sample offset
        const float Cs = __shfl(C, row, 64);     // lane 'row' owns that sample's C
        const int s = gbase + row;
        if (s < B) {
            float* ob = out + (size_t)s * 75;
            const float v0 = acc0[r] + Cs * wsum0;
            ob[3 * m]     = v0;
            ob[3 * m + 1] = v0;
            ob[3 * m + 2] = v0;
            if (m <= 8) {
                const int k = 16 + m;
                const float v1 = acc1[r] + Cs * wsum1;
                ob[3 * k]     = v1;
                ob[3 * k + 1] = v1;
                ob[3 * k + 2] = v1;
            }
        }
    }
}

extern "C" void kernel_launch(void* const* d_in, const int* in_sizes, int n_in,
                              void* d_out, int out_size, void* d_ws, size_t ws_size,
                              hipStream_t stream) {
    // inputs: [0] lightid (int32, B — unused), [1] iternum (int32 scalar),
    //         [2] bases (f32, 25*16*32)
    const int*   iternum = (const int*)d_in[1];
    const float* bases   = (const float*)d_in[2];
    float* out = (float*)d_out;
    float* ws  = (float*)d_ws;
    const int B = in_sizes[0];

    hipLaunchKernelGGL(sh_prep_kernel, dim3(30), dim3(256), 0, stream, bases, ws);
    hipLaunchKernelGGL(sh_proj_kernel, dim3((B + 63) / 64), dim3(256), 0, stream,
                       iternum, ws, out, B);
}

// Round 5
// 18.070 us; speedup vs baseline: 7.8623x; 1.3661x over previous
//
#include <hip/hip_runtime.h>
#include <math.h>

// SHLightRotateDecorator — B samples x 512 sphere pixels -> 25 SH coeffs (x3 RGB).
//
// R3: row-symmetry fold (th_y + th_{15-y} = PI_A, light.y == 0 -> dot[y]==dot[15-y])
//     => K=256 folded pixels, folded weights w~.
// R4: PERIODICITY. ph0 = (iternum*B + b)*PI_A/100, so ph0(b+200) = ph0(b) + 2*PI_A.
//     2*PI_A differs from 2*pi by 1.07e-7 rad; across q <= B/200 = 327 periods the
//     light-angle drift is <= 3.5e-5 rad -> delta(proj) <~ 4e-3, far under the
//     0.14 threshold. So the output is a 200-row table tiled:
//        out[b] = tbl[b mod 200],  i.e. flat: out[i] = tbl_flat[i mod 15000].
//     15000 % 4 == 0 -> exact float4 tiling: out4[i] = tbl4[i mod 3750].
//     => transcendental work drops 327x; the op becomes write-BW-bound (19.7 MB).
//     fp16/MFMA path dropped entirely (f32 weights -> smaller absmax).
//
// lm math (single pass): lm = log(1e-5 + exp(-4*acos(dot)^2)) <= ~1e-5 so
// lse = log(S) directly; normalization is linear post-log:
//   proj_k = sum_p lm_p*w~[p][k] + ((7 - log(2S)) + 0.001)*wsum_k.

#define PI_A 3.1415926
#define NPI  3.14159265358979323846

#if __has_builtin(__builtin_amdgcn_sqrtf)
#define FSQRT __builtin_amdgcn_sqrtf
#else
#define FSQRT sqrtf
#endif
#if __has_builtin(__builtin_amdgcn_exp2f)
#define FEXP2 __builtin_amdgcn_exp2f
#else
#define FEXP2 exp2f
#endif
#if __has_builtin(__builtin_amdgcn_logf)
#define FLOG2 __builtin_amdgcn_logf
#else
#define FLOG2 log2f
#endif

// ws layout (floats):
//   [0, 6400)      wt[256][25]  folded weights, f32
//   [6400, 6432)   wsum[32]     (sum over FULL 512 grid == sum of folded w~)
//   [6432, 21432)  tbl[200][75] projected table, RGB-expanded
//   (6432*4 = 25728 B, 16B-aligned -> float4 loads OK)
#define WT_OFF   0
#define WSUM_OFF 6400
#define TBL_OFF  6432

__global__ __launch_bounds__(256) void sh_prep_kernel(
        const float* __restrict__ bases, float* __restrict__ ws) {
    const int tid = threadIdx.x;
    const int k   = blockIdx.x;           // one block per coeff, k in [0,25)
    const float KC = (float)(NPI * NPI / 512.0);  // np.pi^2 / numel (true pi!)

    const int p = tid;                    // folded pixel, y<8
    const int y = p >> 5, x = p & 31;
    const float th_lo = (float)(((double)y + 0.5) * PI_A / 16.0);
    const float th_hi = (float)(((double)(15 - y) + 0.5) * PI_A / 16.0);
    const float v = bases[k * 512 + p] * (sinf(th_lo) * KC)
                  + bases[k * 512 + ((15 - y) << 5) + x] * (sinf(th_hi) * KC);
    ws[WT_OFF + p * 25 + k] = v;

    // wsum[k]: the fold preserves the full-grid sum exactly
    float s = v;
#pragma unroll
    for (int off = 32; off; off >>= 1) s += __shfl_down(s, off, 64);
    __shared__ float red[4];
    if ((tid & 63) == 0) red[tid >> 6] = s;
    __syncthreads();
    if (tid == 0) ws[WSUM_OFF + k] = red[0] + red[1] + red[2] + red[3];
}

// One block per table row j in [0,200): sample b=j's projection.
__global__ __launch_bounds__(256) void sh_table_kernel(
        const int* __restrict__ iternum_p, float* __restrict__ ws, int B) {
    __shared__ float lmbuf[8 * 33];    // [group][32], stride 33: conflict-free
    __shared__ float partial[8][26];
    __shared__ float Sred[4];

    const int tid = threadIdx.x;
    const int j   = blockIdx.x;

    // light dir for sample j, f64 (ph0 ~ 2e6 rad; f32 ulp there is 0.125 rad)
    const long long n = (long long)(*iternum_p) * (long long)B + (long long)j;
    const double ph0 = ((double)n * 2.0) * PI_A / 200.0;
    const float sld = (float)sin(ph0);
    const float cld = (float)cos(ph0);

    // per-pixel chain (folded grid: rows y<8)
    const int y = tid >> 5, x = tid & 31;
    const float th = (float)(((double)y + 0.5) * PI_A / 16.0);
    const float ph = (float)(((double)x + 0.5) * PI_A / 16.0);
    const float st  = sinf(th);
    const float drx = st * sinf(ph);
    const float drz = st * cosf(ph);
    float dot = fminf(1.0f, fmaxf(-1.0f, sld * drx + cld * drz));
    // fast acos (Hastings, |err|~1.8e-4 rad)
    const float ax = fabsf(dot);
    const float sq = FSQRT(1.0f - ax);
    const float P  = fmaf(fmaf(fmaf(-0.0187293f, ax, 0.0742610f),
                               ax, -0.2121144f), ax, 1.5707288f);
    const float r_ = sq * P;
    const float a  = (dot < 0.0f) ? (3.14159265f - r_) : r_;
    const float c1 = -4.0f * 1.4426950408889634f;
    const float ln2 = 0.6931471805599453f;
    const float ex = FEXP2(a * a * c1);
    const float e  = 1e-5f + ex;
    const float lm = FLOG2(e) * ln2;
    lmbuf[(tid >> 5) * 33 + (tid & 31)] = lm;

    float s = e;
#pragma unroll
    for (int off = 32; off; off >>= 1) s += __shfl_down(s, off, 64);
    if ((tid & 63) == 0) Sred[tid >> 6] = s;
    __syncthreads();

    // phase 2: group g handles pixels [g*32, g*32+32), lane k accumulates coeff k
    const int g = tid >> 5, k = tid & 31;
    if (k < 25) {
        float acc = 0.0f;
#pragma unroll
        for (int j2 = 0; j2 < 32; ++j2) {
            acc = fmaf(lmbuf[g * 33 + j2],
                       ws[WT_OFF + (g * 32 + j2) * 25 + k], acc);
        }
        partial[g][k] = acc;
    }
    __syncthreads();

    if (tid < 25) {
        float tot = 0.0f;
#pragma unroll
        for (int gg = 0; gg < 8; ++gg) tot += partial[gg][tid];
        const float S = Sred[0] + Sred[1] + Sred[2] + Sred[3];
        const float C = (7.0f - FLOG2(2.0f * S) * ln2) + 0.001f;
        const float v = tot + C * ws[WSUM_OFF + tid];
        float* tb = ws + TBL_OFF + j * 75 + 3 * tid;
        tb[0] = v; tb[1] = v; tb[2] = v;   // RGB repeat
    }
}

// out is the table tiled: out4[i] = tbl4[i mod 3750]  (exact flat-layout identity)
__global__ __launch_bounds__(256) void sh_bcast_kernel(
        const float* __restrict__ ws, float4* __restrict__ out, int total4) {
    const float4* t4 = (const float4*)(ws + TBL_OFF);
    int i = blockIdx.x * 256 + threadIdx.x;
    const int stride = gridDim.x * 256;
    for (; i < total4; i += stride)
        out[i] = t4[i % 3750];
}

extern "C" void kernel_launch(void* const* d_in, const int* in_sizes, int n_in,
                              void* d_out, int out_size, void* d_ws, size_t ws_size,
                              hipStream_t stream) {
    // inputs: [0] lightid (int32, B — unused), [1] iternum (int32 scalar),
    //         [2] bases (f32, 25*16*32)
    const int* iternum = (const int*)d_in[1];
    const float* bases = (const float*)d_in[2];
    float* ws = (float*)d_ws;
    const int B = in_sizes[0];
    const int total4 = out_size / 4;   // out_size = B*75, B multiple of 4

    hipLaunchKernelGGL(sh_prep_kernel, dim3(25), dim3(256), 0, stream, bases, ws);
    hipLaunchKernelGGL(sh_table_kernel, dim3(200), dim3(256), 0, stream,
                       iternum, ws, B);
    int nblk = (total4 + 255) / 256;
    if (nblk > 2048) nblk = 2048;
    hipLaunchKernelGGL(sh_bcast_kernel, dim3(nblk), dim3(256), 0, stream,
                       ws, (float4*)d_out, total4);
}

// Round 6
// 14.876 us; speedup vs baseline: 9.5506x; 1.2147x over previous
//
#include <hip/hip_runtime.h>
#include <math.h>

// SHLightRotateDecorator — B samples x 512 sphere pixels -> 25 SH coeffs (x3 RGB).
//
// R3: row-symmetry fold (th_y + th_{15-y} = PI_A, light.y == 0 -> dot[y]==dot[15-y])
//     => 256 folded pixels, folded weights w~.
// R4: periodicity: ph0(b+200) = ph0(b) + 2*PI_A (drift <= 3.5e-5 rad over all
//     B/200 = 327 periods) => output is a 200-row table tiled: out[b] = tbl[b%200].
// R5: SINGLE-KERNEL FUSION. 3 dispatches (prep/table/bcast) cost ~11 us in launch
//     gaps vs ~6 us of work. Invert the broadcast: block (j, s) computes table row
//     j itself (w~ built redundantly in LDS from bases — 50 KB, L2-resident) and
//     writes replicas b = j + 200*s + 800*rr directly. No inter-block dependency,
//     no workspace, one dispatch.
//
// lm math (single pass): lm = log(1e-5 + exp(-4*acos(dot)^2)) <= ~1e-5 so
// lse = log(S) directly; normalization is linear post-log:
//   proj_k = sum_p lm_p*w~[p][k] + ((7 - log(2S)) + 0.001)*wsum_k.

#define PI_A 3.1415926
#define NPI  3.14159265358979323846
#define SPLIT 4   // blocks per table row; grid = 200*SPLIT

#if __has_builtin(__builtin_amdgcn_sqrtf)
#define FSQRT __builtin_amdgcn_sqrtf
#else
#define FSQRT sqrtf
#endif
#if __has_builtin(__builtin_amdgcn_exp2f)
#define FEXP2 __builtin_amdgcn_exp2f
#else
#define FEXP2 exp2f
#endif
#if __has_builtin(__builtin_amdgcn_logf)
#define FLOG2 __builtin_amdgcn_logf
#else
#define FLOG2 log2f
#endif

__global__ __launch_bounds__(256) void sh_fused_kernel(
        const int* __restrict__ iternum_p, const float* __restrict__ bases,
        float* __restrict__ out, int B) {
    __shared__ float wt[256 * 25];     // folded weights w~[p][k]
    __shared__ float lmbuf[8 * 33];    // stride 33: conflict-free
    __shared__ float partial[8][26];   // sum lm*w~ per 32-pixel group
    __shared__ float wpartial[8][26];  // sum w~ per group (for wsum)
    __shared__ float Sred[4];
    __shared__ float vrow[76];         // the 75 output floats of this row

    const int tid = threadIdx.x;
    const int j   = blockIdx.x % 200;  // table row (= b mod 200)
    const int s   = blockIdx.x / 200;  // replica split

    const float KC  = (float)(NPI * NPI / 512.0);  // np.pi^2/numel (true pi!)
    const float ln2 = 0.6931471805599453f;

    // ---- folded weights into LDS (coalesced bases reads: thread = pixel) ----
    const int p = tid, y = p >> 5, x = p & 31;
    const float th_lo = (float)(((double)y + 0.5) * PI_A / 16.0);
    const float th_hi = (float)(((double)(15 - y) + 0.5) * PI_A / 16.0);
    const float st_lo = sinf(th_lo) * KC;
    const float st_hi = sinf(th_hi) * KC;
    const int mir = ((15 - y) << 5) + x;
#pragma unroll
    for (int k = 0; k < 25; ++k)
        wt[p * 25 + k] = bases[k * 512 + p] * st_lo + bases[k * 512 + mir] * st_hi;

    // ---- light dir for row j: f64 (ph0 ~ 2e6 rad; f32 ulp = 0.125 rad) ----
    const long long n = (long long)(*iternum_p) * (long long)B + (long long)j;
    const double ph0 = ((double)n * 2.0) * PI_A / 200.0;
    const float sld = (float)sin(ph0);
    const float cld = (float)cos(ph0);

    // ---- per-pixel chain (folded grid, rows y<8) ----
    const float ph  = (float)(((double)x + 0.5) * PI_A / 16.0);
    const float st  = sinf(th_lo);
    const float drx = st * sinf(ph);
    const float drz = st * cosf(ph);
    float dot = fminf(1.0f, fmaxf(-1.0f, sld * drx + cld * drz));
    const float ax = fabsf(dot);                    // fast acos (Hastings)
    const float sq = FSQRT(1.0f - ax);
    const float P  = fmaf(fmaf(fmaf(-0.0187293f, ax, 0.0742610f),
                               ax, -0.2121144f), ax, 1.5707288f);
    const float r_ = sq * P;
    const float a  = (dot < 0.0f) ? (3.14159265f - r_) : r_;
    const float c1 = -4.0f * 1.4426950408889634f;
    const float ex = FEXP2(a * a * c1);
    const float e  = 1e-5f + ex;
    const float lm = FLOG2(e) * ln2;
    lmbuf[y * 33 + x] = lm;

    float sr = e;
#pragma unroll
    for (int off = 32; off; off >>= 1) sr += __shfl_down(sr, off, 64);
    if ((tid & 63) == 0) Sred[tid >> 6] = sr;
    __syncthreads();

    // ---- projection: group g = 32 pixels, lane k = coeff ----
    const int g = tid >> 5, k = tid & 31;
    if (k < 25) {
        float acc = 0.0f, wacc = 0.0f;
#pragma unroll
        for (int j2 = 0; j2 < 32; ++j2) {
            const float w = wt[(g * 32 + j2) * 25 + k];
            acc  = fmaf(lmbuf[g * 33 + j2], w, acc);
            wacc += w;
        }
        partial[g][k]  = acc;
        wpartial[g][k] = wacc;
    }
    __syncthreads();

    if (tid < 25) {
        float tot = 0.0f, wsum = 0.0f;
#pragma unroll
        for (int gg = 0; gg < 8; ++gg) { tot += partial[gg][tid]; wsum += wpartial[gg][tid]; }
        const float S = Sred[0] + Sred[1] + Sred[2] + Sred[3];
        const float C = (7.0f - FLOG2(2.0f * S) * ln2) + 0.001f;
        const float v = tot + C * wsum;
        vrow[3 * tid] = v; vrow[3 * tid + 1] = v; vrow[3 * tid + 2] = v;
    }
    __syncthreads();

    // ---- write this row's replicas: b = j + 200*s + 800*rr ----
    const int b0 = j + 200 * s;
    const int nrep = (B - b0 + 200 * SPLIT - 1) / (200 * SPLIT);
    float* pb = out + (size_t)b0 * 75;
    int rr = tid / 75, o = tid - rr * 75;      // flat idx = rr*75 + o, step 256
    while (rr < nrep) {
        pb[(size_t)rr * (200 * SPLIT * 75) + o] = vrow[o];
        o += 31; rr += 3;                       // += 256 = 3*75 + 31
        if (o >= 75) { o -= 75; rr += 1; }
    }
}

extern "C" void kernel_launch(void* const* d_in, const int* in_sizes, int n_in,
                              void* d_out, int out_size, void* d_ws, size_t ws_size,
                              hipStream_t stream) {
    // inputs: [0] lightid (int32, B — unused), [1] iternum (int32 scalar),
    //         [2] bases (f32, 25*16*32)
    const int* iternum = (const int*)d_in[1];
    const float* bases = (const float*)d_in[2];
    float* out = (float*)d_out;
    const int B = in_sizes[0];

    hipLaunchKernelGGL(sh_fused_kernel, dim3(200 * SPLIT), dim3(256), 0, stream,
                       iternum, bases, out, B);
}

// Round 7
// 14.638 us; speedup vs baseline: 9.7057x; 1.0162x over previous
//
#include <hip/hip_runtime.h>
#include <math.h>

// SHLightRotateDecorator — B samples x 512 sphere pixels -> 25 SH coeffs (x3 RGB).
//
// R3: row-symmetry fold (th_y + th_{15-y} = PI_A, light.y == 0 -> dot[y]==dot[15-y])
//     => 256 folded pixels, folded weights w~.
// R4: periodicity: ph0(b+200) = ph0(b) + 2*PI_A (drift <= 3.5e-5 rad over the
//     call's 327 periods) => output is a 200-row table tiled: out[b] = tbl[b%200].
// R5: single-kernel fusion: block computes its table row from bases directly
//     (no inter-block deps, no ws) and writes its replicas.
// R6: 4 ROWS PER BLOCK -> replica groups are 300 contiguous floats = 75 aligned
//     float4 stores (was misaligned 300B scalar runs). Rows share: one f64
//     sincos + exact f64 rotation (dlt = PI_A/100) for the other 3 light dirs;
//     dr once; wt ds_read once per pixel serves 4 rows; lm packed float4 in LDS.
//
// lm math (single pass): lm = log(1e-5 + exp(-4*acos(dot)^2)) <= ~1e-5 so
// lse = log(S) directly; normalization is linear post-log:
//   proj_k = sum_p lm_p*w~[p][k] + ((7 - log(2S)) + 0.001)*wsum_k.

#define PI_A 3.1415926
#define NPI  3.14159265358979323846
#define NG    50                      // groups of 4 table rows (200 rows total)
#define SPLIT 16                      // replica splits; grid = NG*SPLIT = 800
#define STRIDE_ROWS (4 * NG * SPLIT)  // 3200 rows between a block's replica groups

#if __has_builtin(__builtin_amdgcn_sqrtf)
#define FSQRT __builtin_amdgcn_sqrtf
#else
#define FSQRT sqrtf
#endif
#if __has_builtin(__builtin_amdgcn_exp2f)
#define FEXP2 __builtin_amdgcn_exp2f
#else
#define FEXP2 exp2f
#endif
#if __has_builtin(__builtin_amdgcn_logf)
#define FLOG2 __builtin_amdgcn_logf
#else
#define FLOG2 log2f
#endif

__global__ __launch_bounds__(256) void sh_fused_kernel(
        const int* __restrict__ iternum_p, const float* __restrict__ bases,
        float* __restrict__ out, int B) {
    __shared__ float  wt[256 * 25];      // folded weights w~[p][k]        (25600 B)
    __shared__ float4 lm4[8][32];        // per-pixel lm for the 4 rows    (4096 B)
    __shared__ float  partial[4][8][26]; // sum lm*w~ per row, 32-px group (3328 B)
    __shared__ float  wpartial[8][26];   // sum w~ per group (row-indep)   (832 B)
    __shared__ float  Sred[4][4];        // [wave][row] partial S          (64 B)
    __shared__ float4 vrow4[75];         // 4 rows x 75 floats, contiguous (1200 B)

    const int tid = threadIdx.x;
    const int g   = blockIdx.x % NG;
    const int s   = blockIdx.x / NG;
    const int j0  = 4 * g;               // first table row of this block

    const float KC  = (float)(NPI * NPI / 512.0);  // np.pi^2/numel (true pi!)
    const float ln2 = 0.6931471805599453f;
    const float c1  = -4.0f * 1.4426950408889634f; // -4*log2(e)

    // ---- folded weights into LDS (coalesced bases reads: thread = pixel) ----
    const int p = tid, y = p >> 5, x = p & 31;
    const float th_lo = (float)(((double)y + 0.5) * PI_A / 16.0);
    const float th_hi = (float)(((double)(15 - y) + 0.5) * PI_A / 16.0);
    const float st_lo = sinf(th_lo) * KC;
    const float st_hi = sinf(th_hi) * KC;
    const int mir = ((15 - y) << 5) + x;
#pragma unroll
    for (int k = 0; k < 25; ++k)
        wt[p * 25 + k] = bases[k * 512 + p] * st_lo + bases[k * 512 + mir] * st_hi;

    // ---- light dirs for rows j0..j0+3: one full-range f64 sincos (ph0 ~ 2e6
    //      rad; f32 ulp = 0.125 rad) + exact f64 rotation by dlt = PI_A/100 ----
    const long long n = (long long)(*iternum_p) * (long long)B + (long long)j0;
    const double ph0 = ((double)n * 2.0) * PI_A / 200.0;
    const double dlt = PI_A / 100.0;
    const double cD = cos(dlt), sD = sin(dlt);
    double sd = sin(ph0), cd = cos(ph0);
    float sld[4], cld[4];
#pragma unroll
    for (int r = 0; r < 4; ++r) {
        sld[r] = (float)sd; cld[r] = (float)cd;
        const double s2 = sd * cD + cd * sD;
        cd = cd * cD - sd * sD;
        sd = s2;
    }

    // ---- per-pixel chain (folded grid, rows y<8), 4 light rows ----
    const float ph  = (float)(((double)x + 0.5) * PI_A / 16.0);
    const float st  = sinf(th_lo);
    const float drx = st * sinf(ph);
    const float drz = st * cosf(ph);
    float4 lmv; float sr[4];
#pragma unroll
    for (int r = 0; r < 4; ++r) {
        float dot = fminf(1.0f, fmaxf(-1.0f, sld[r] * drx + cld[r] * drz));
        const float ax = fabsf(dot);                    // fast acos (Hastings)
        const float sq = FSQRT(1.0f - ax);
        const float P  = fmaf(fmaf(fmaf(-0.0187293f, ax, 0.0742610f),
                                   ax, -0.2121144f), ax, 1.5707288f);
        const float r_ = sq * P;
        const float a  = (dot < 0.0f) ? (3.14159265f - r_) : r_;
        const float ex = FEXP2(a * a * c1);
        const float e  = 1e-5f + ex;
        sr[r] = e;
        const float lm = FLOG2(e) * ln2;
        if (r == 0) lmv.x = lm; else if (r == 1) lmv.y = lm;
        else if (r == 2) lmv.z = lm; else lmv.w = lm;
    }
    lm4[y][x] = lmv;
#pragma unroll
    for (int r = 0; r < 4; ++r) {
#pragma unroll
        for (int off = 32; off; off >>= 1) sr[r] += __shfl_down(sr[r], off, 64);
    }
    if ((tid & 63) == 0) {
        const int wv = tid >> 6;
        Sred[wv][0] = sr[0]; Sred[wv][1] = sr[1];
        Sred[wv][2] = sr[2]; Sred[wv][3] = sr[3];
    }
    __syncthreads();

    // ---- projection: group g2 = 32 pixels, lane k = coeff; 4 rows at once ----
    const int g2 = tid >> 5, k = tid & 31;
    if (k < 25) {
        float a0 = 0.f, a1 = 0.f, a2 = 0.f, a3 = 0.f, wacc = 0.f;
#pragma unroll
        for (int j2 = 0; j2 < 32; ++j2) {
            const float  w = wt[(g2 * 32 + j2) * 25 + k];
            const float4 l = lm4[g2][j2];               // one ds_read_b128, 4 rows
            a0 = fmaf(l.x, w, a0); a1 = fmaf(l.y, w, a1);
            a2 = fmaf(l.z, w, a2); a3 = fmaf(l.w, w, a3);
            wacc += w;
        }
        partial[0][g2][k] = a0; partial[1][g2][k] = a1;
        partial[2][g2][k] = a2; partial[3][g2][k] = a3;
        wpartial[g2][k] = wacc;
    }
    __syncthreads();

    // ---- finalize: thread (r, k) for tid < 100 ----
    if (tid < 100) {
        const int r = tid / 25, kk = tid % 25;
        float tot = 0.0f, wsum = 0.0f;
#pragma unroll
        for (int gg = 0; gg < 8; ++gg) {
            tot  += partial[r][gg][kk];
            wsum += wpartial[gg][kk];
        }
        const float S = Sred[0][r] + Sred[1][r] + Sred[2][r] + Sred[3][r];
        const float C = (7.0f - FLOG2(2.0f * S) * ln2) + 0.001f;
        const float v = tot + C * wsum;
        float* vr = (float*)vrow4 + r * 75 + 3 * kk;
        vr[0] = v; vr[1] = v; vr[2] = v;                // RGB repeat
    }
    __syncthreads();

    // ---- write replicas: rows b0+STRIDE_ROWS*rr .. +3, as 75 float4s each ----
    const int b0 = j0 + 200 * s;                        // multiple of 4
    const int ngroups = (b0 < B) ? (B - b0 + STRIDE_ROWS - 1) / STRIDE_ROWS : 0;
    float4* ob4 = (float4*)out + (size_t)(b0 / 4) * 75;
    const size_t gstride = (size_t)STRIDE_ROWS * 75 / 4;  // 60000 float4
    int rr = tid / 75;                                  // 0..3
    int q  = tid - rr * 75;
    while (rr < ngroups) {
        ob4[(size_t)rr * gstride + q] = vrow4[q];
        rr += 3; q += 31;                               // advance flat idx by 256
        if (q >= 75) { q -= 75; ++rr; }
    }
}

extern "C" void kernel_launch(void* const* d_in, const int* in_sizes, int n_in,
                              void* d_out, int out_size, void* d_ws, size_t ws_size,
                              hipStream_t stream) {
    // inputs: [0] lightid (int32, B — unused), [1] iternum (int32 scalar),
    //         [2] bases (f32, 25*16*32)
    const int* iternum = (const int*)d_in[1];
    const float* bases = (const float*)d_in[2];
    float* out = (float*)d_out;
    const int B = in_sizes[0];

    hipLaunchKernelGGL(sh_fused_kernel, dim3(NG * SPLIT), dim3(256), 0, stream,
                       iternum, bases, out, B);
}